// Round 3
// baseline (359.829 us; speedup 1.0000x reference)
//
#include <hip/hip_runtime.h>

// DenselyCnnAttLayer: B=64, S=512, L=6, D=512, fp32.
//
// R3 structure: ONE wave per (b,s) position, full D=512.
//  - Each lane holds 2 float4 per input array (48 floats, 12 KB/wave in
//    flight) -> 2x the per-wave MLP of the old 2-wave split.
//  - No LDS, no __syncthreads: the old version coupled 4 waves through a
//    block barrier around an LDS combine; every wave now free-runs.
//  - Butterfly/logits/softmax computed once per position, not twice.
// R0-R2 post-mortem: three source variants produced byte-identical
// counters (VGPR 28, FETCH 196.8MB, 140us) -> loads were already
// back-to-back; the serialized-loads theory was wrong. The remaining
// structural differences vs a 6.3TB/s copy kernel were per-wave bytes in
// flight, the barrier lockstep, and duplicated reduction work.
//
// Remat guard: a SINGLE asm with all 12 float4s as "+v" operands makes
// the loaded values asm *outputs* -- reloading from memory is illegal, so
// the compiler cannot rematerialize the loads after softmax (the failure
// mode a previous session hit with 48 live floats and per-value KEEPs).
constexpr int Bc = 64, Sc = 512, Lc = 6, Dc = 512;

typedef float f32x4 __attribute__((ext_vector_type(4)));

#define KEEP12(v)                                                       \
    asm volatile(""                                                     \
        : "+v"((v)[0][0]), "+v"((v)[0][1]),                             \
          "+v"((v)[1][0]), "+v"((v)[1][1]),                             \
          "+v"((v)[2][0]), "+v"((v)[2][1]),                             \
          "+v"((v)[3][0]), "+v"((v)[3][1]),                             \
          "+v"((v)[4][0]), "+v"((v)[4][1]),                             \
          "+v"((v)[5][0]), "+v"((v)[5][1]))

__global__ __launch_bounds__(256) void densely_att_kernel(
    const float* __restrict__ x0, const float* __restrict__ x1,
    const float* __restrict__ x2, const float* __restrict__ x3,
    const float* __restrict__ x4, const float* __restrict__ x5,
    const float* __restrict__ Ws, float* __restrict__ out)
{
    const int wave = threadIdx.x >> 6;     // 0..3 : position within block
    const int lane = threadIdx.x & 63;

    const long pos = (long)blockIdx.x * 4 + wave;        // b*S + s
    const int s_idx = __builtin_amdgcn_readfirstlane((int)(pos % Sc));

    const float* xs[Lc] = {x0, x1, x2, x3, x4, x5};

    // Lane covers d = lane*4..+3 and d = 256 + lane*4..+3.
    const size_t b0 = (size_t)pos * Dc + (size_t)lane * 4;
    const size_t b1 = b0 + 256;

    // ---- Issue all 12 loads back-to-back; pin all 48 floats at ONE point.
    f32x4 v[Lc][2];
    #pragma unroll
    for (int j = 0; j < Lc; ++j) {
        v[j][0] = *(const f32x4*)(xs[j] + b0);
        v[j][1] = *(const f32x4*)(xs[j] + b1);
    }
    KEEP12(v);

    float ssum[Lc];
    #pragma unroll
    for (int j = 0; j < Lc; ++j) {
        f32x4 t = v[j][0] + v[j][1];
        ssum[j] = (t.x + t.y) + (t.z + t.w);
    }

    // Butterfly reduce across the 64-lane wave -> full sum over D.
    #pragma unroll
    for (int off = 32; off >= 1; off >>= 1) {
        #pragma unroll
        for (int j = 0; j < Lc; ++j)
            ssum[j] += __shfl_xor(ssum[j], off, 64);
    }

    // logits[m] = sum_l ssum[l] * Ws[s, l, m];  Ws is (S, L, L) row-major
    const float* __restrict__ w = Ws + (size_t)s_idx * (Lc * Lc);
    float logits[Lc];
    #pragma unroll
    for (int m = 0; m < Lc; ++m) {
        float acc = 0.f;
        #pragma unroll
        for (int l = 0; l < Lc; ++l)
            acc = fmaf(ssum[l], w[l * Lc + m], acc);
        logits[m] = acc;
    }

    // softmax over L (6 values, cheap)
    float mx = logits[0];
    #pragma unroll
    for (int m = 1; m < Lc; ++m) mx = fmaxf(mx, logits[m]);
    float a[Lc];
    float denom = 0.f;
    #pragma unroll
    for (int m = 0; m < Lc; ++m) {
        a[m] = __expf(logits[m] - mx);
        denom += a[m];
    }
    const float inv = 1.f / denom;
    #pragma unroll
    for (int m = 0; m < Lc; ++m) a[m] *= inv;

    // out[d] = sum_j a[j] * x_j[d]  (x values still live in VGPRs)
    f32x4 o0 = {0.f, 0.f, 0.f, 0.f};
    f32x4 o1 = {0.f, 0.f, 0.f, 0.f};
    #pragma unroll
    for (int j = 0; j < Lc; ++j) {
        o0 += a[j] * v[j][0];
        o1 += a[j] * v[j][1];
    }
    __builtin_nontemporal_store(o0, (f32x4*)(out + b0));
    __builtin_nontemporal_store(o1, (f32x4*)(out + b1));
}

extern "C" void kernel_launch(void* const* d_in, const int* in_sizes, int n_in,
                              void* d_out, int out_size, void* d_ws, size_t ws_size,
                              hipStream_t stream) {
    const float* x0 = (const float*)d_in[0];
    const float* x1 = (const float*)d_in[1];
    const float* x2 = (const float*)d_in[2];
    const float* x3 = (const float*)d_in[3];
    const float* x4 = (const float*)d_in[4];
    const float* x5 = (const float*)d_in[5];
    const float* Ws = (const float*)d_in[6];
    float* out = (float*)d_out;

    const int positions = Bc * Sc;            // 32768
    const int blocks = positions / 4;         // 1 position per wave, 4 waves/block
    densely_att_kernel<<<blocks, 256, 0, stream>>>(x0, x1, x2, x3, x4, x5, Ws, out);
}